// Round 5
// baseline (459.856 us; speedup 1.0000x reference)
//
#include <hip/hip_runtime.h>

// SpMM: out[b,m] = bias[m] + sum_{e: dst[e]==m} values[e] * x[b, src[e]]
// B=32, N=M=50000, E=1600000.
// v6: rounds 2-4 post-mortem: k_accum pinned at 347us across three source
// structures, VGPR=16/16/20 -> hipcc serializes the gather chain (1 load in
// flight) no matter how the source is shaped. Fix: inline-asm pipeline.
// 8 volatile global_load_dword issues per slot (mutual order guaranteed),
// one s_waitcnt vmcnt(0) asm with "+v"-tied results (consumers data-depend
// on the wait), then 8 FMA + LDS atomicAdd. This is the documented CDNA
// pattern: compiler defeats source-level pipelining; pin it with asm.

#define BATCH 32
#define DPB   64              // dsts per bucket -> NB = 782
#define ACC_TPB 1024
#define ACC_TILE 2560         // sv entries staged per round (20KB)
#define ACC_DEPTH 8           // forced-in-flight gathers per slot
#define BIN_TPB 1024
#define BIN_EPT 4             // chunk = 4096 edges

// ---- transpose x (B,N) -> xt (N,B), LDS tiled ----
__global__ void k_transpose_x(const float* __restrict__ x, float* __restrict__ xt, int N) {
    __shared__ float tile[32][33];
    const int n0 = blockIdx.x * 32;
    const int tx = threadIdx.x;   // 0..31
    const int ty = threadIdx.y;   // 0..7
    #pragma unroll
    for (int k = 0; k < 4; ++k) {
        const int b = ty + 8 * k;
        const int n = n0 + tx;
        tile[tx][b] = (n < N) ? x[(size_t)b * N + n] : 0.0f;
    }
    __syncthreads();
    #pragma unroll
    for (int k = 0; k < 4; ++k) {
        const int n = n0 + ty + 8 * k;
        if (n < N) xt[(size_t)n * BATCH + tx] = tile[ty + 8 * k][tx];
    }
}

__global__ void k_zero_i32(int* __restrict__ p, int n) {
    const int i = blockIdx.x * blockDim.x + threadIdx.x;
    if (i < n) p[i] = 0;
}

// ---- per-bucket global histogram via LDS staging ----
__global__ __launch_bounds__(256) void k_bucket_count(const int* __restrict__ idx,
                                                      int* __restrict__ gcount,
                                                      int E, int NB) {
    extern __shared__ int hist[];
    for (int i = threadIdx.x; i < NB; i += blockDim.x) hist[i] = 0;
    __syncthreads();
    const int stride = gridDim.x * blockDim.x;
    for (int e = blockIdx.x * blockDim.x + threadIdx.x; e < E; e += stride) {
        atomicAdd(&hist[idx[E + e] / DPB], 1);
    }
    __syncthreads();
    for (int i = threadIdx.x; i < NB; i += blockDim.x) {
        if (hist[i]) atomicAdd(&gcount[i], hist[i]);
    }
}

// ---- single-wg exclusive scan of bucket counts (NB <= 1024) ----
__global__ __launch_bounds__(1024) void k_scan_buckets(const int* __restrict__ gcount,
                                                       int* __restrict__ bucket_base,
                                                       int* __restrict__ gcursor,
                                                       int NB, int E) {
    __shared__ int s[1024];
    const int tid = threadIdx.x;
    const int v = (tid < NB) ? gcount[tid] : 0;
    s[tid] = v;
    __syncthreads();
    for (int off = 1; off < 1024; off <<= 1) {
        const int t = (tid >= off) ? s[tid - off] : 0;
        __syncthreads();
        s[tid] += t;
        __syncthreads();
    }
    if (tid < NB) {
        const int excl = s[tid] - v;
        bucket_base[tid] = excl;
        gcursor[tid] = excl;
    }
    if (tid == 0) bucket_base[NB] = E;
}

// ---- bin edges into bucket-contiguous segments, packed (src|dl<<16, val) ----
__global__ __launch_bounds__(BIN_TPB) void k_bin(const int* __restrict__ idx,
                                                 const float* __restrict__ values,
                                                 int* __restrict__ gcursor,
                                                 int2* __restrict__ sv,
                                                 int E, int NB) {
    extern __shared__ int lds[];
    int* hist = lds;          // [NB] counts, then reused as local cursor
    int* base = lds + NB;     // [NB] this chunk's global segment base
    for (int i = threadIdx.x; i < NB; i += BIN_TPB) hist[i] = 0;
    __syncthreads();

    const int c0 = blockIdx.x * (BIN_TPB * BIN_EPT);
    int d[BIN_EPT];
    #pragma unroll
    for (int i = 0; i < BIN_EPT; ++i) {
        const int e = c0 + threadIdx.x + i * BIN_TPB;
        d[i] = (e < E) ? idx[E + e] : -1;
        if (d[i] >= 0) atomicAdd(&hist[d[i] / DPB], 1);
    }
    __syncthreads();
    // reserve contiguous global segments, reset local cursors
    for (int i = threadIdx.x; i < NB; i += BIN_TPB) {
        const int c = hist[i];
        base[i] = c ? atomicAdd(&gcursor[i], c) : 0;
        hist[i] = 0;
    }
    __syncthreads();
    #pragma unroll
    for (int i = 0; i < BIN_EPT; ++i) {
        if (d[i] >= 0) {
            const int e = c0 + threadIdx.x + i * BIN_TPB;
            const int bkt = d[i] / DPB;
            const int off = atomicAdd(&hist[bkt], 1);
            const int packed = (idx[e] & 0xFFFF) | ((d[i] % DPB) << 16);
            sv[base[bkt] + off] = make_int2(packed, __float_as_int(values[e]));
        }
    }
}

// ---- one block per bucket: asm-pinned 8-deep gather pipeline + LDS accum ----
__global__ __launch_bounds__(ACC_TPB, 8) void k_accum(const int2* __restrict__ sv,
                                                      const int* __restrict__ bucket_base,
                                                      const float* __restrict__ xt,
                                                      const float* __restrict__ bias,
                                                      float* __restrict__ out, int M) {
    __shared__ float acc[DPB * 33];      // [dl][b] padded: bank = (dl+b)%32
    __shared__ int2  stage[ACC_TILE];    // staged sv segment
    for (int i = threadIdx.x; i < DPB * 33; i += ACC_TPB) acc[i] = 0.0f;

    const int bkt = blockIdx.x;
    const int beg = bucket_base[bkt];
    const int end = bucket_base[bkt + 1];

    const int slot  = threadIdx.x >> 5;      // 0..31 (half-wave id)
    const int lb    = threadIdx.x & 31;      // batch lane
    const int NSLOT = ACC_TPB / 32;          // 32

    for (int t0 = beg; t0 < end; t0 += ACC_TILE) {
        const int cnt = min(ACC_TILE, end - t0);
        __syncthreads();   // acc init done (1st iter) / prev tile consumed
        for (int i = threadIdx.x; i < cnt; i += ACC_TPB) stage[i] = sv[t0 + i];
        __syncthreads();

        int i = slot;
        for (; i + (ACC_DEPTH - 1) * NSLOT < cnt; i += ACC_DEPTH * NSLOT) {
            float xv0, xv1, xv2, xv3, xv4, xv5, xv6, xv7;
            int   di0, di1, di2, di3, di4, di5, di6, di7;
            float va0, va1, va2, va3, va4, va5, va6, va7;
            // issue 8 independent gathers; volatile asm pins mutual order,
            // so all 8 are in flight before the waitcnt.
            #define GLD(K, XV, DI, VA)                                              \
            {                                                                       \
                const int2 a_ = stage[i + (K) * NSLOT];                             \
                const float* p_ = xt + ((a_.x & 0xFFFF) * BATCH + lb);              \
                asm volatile("global_load_dword %0, %1, off" : "=v"(XV) : "v"(p_)); \
                DI = ((a_.x >> 16) & 63) * 33 + lb;                                 \
                VA = __int_as_float(a_.y);                                          \
            }
            GLD(0, xv0, di0, va0) GLD(1, xv1, di1, va1)
            GLD(2, xv2, di2, va2) GLD(3, xv3, di3, va3)
            GLD(4, xv4, di4, va4) GLD(5, xv5, di5, va5)
            GLD(6, xv6, di6, va6) GLD(7, xv7, di7, va7)
            #undef GLD
            // tie results to the wait: consumers data-depend on this asm
            asm volatile("s_waitcnt vmcnt(0)"
                         : "+v"(xv0), "+v"(xv1), "+v"(xv2), "+v"(xv3),
                           "+v"(xv4), "+v"(xv5), "+v"(xv6), "+v"(xv7));
            atomicAdd(&acc[di0], va0 * xv0);
            atomicAdd(&acc[di1], va1 * xv1);
            atomicAdd(&acc[di2], va2 * xv2);
            atomicAdd(&acc[di3], va3 * xv3);
            atomicAdd(&acc[di4], va4 * xv4);
            atomicAdd(&acc[di5], va5 * xv5);
            atomicAdd(&acc[di6], va6 * xv6);
            atomicAdd(&acc[di7], va7 * xv7);
        }
        for (; i < cnt; i += NSLOT) {
            const int2 a = stage[i];
            const float xa = xt[(size_t)(a.x & 0xFFFF) * BATCH + lb];
            atomicAdd(&acc[((a.x >> 16) & 63) * 33 + lb], __int_as_float(a.y) * xa);
        }
    }
    __syncthreads();

    // epilogue: out[b][m0+d] = acc[d][b] + bias[m0+d]; coalesced along d
    const int m0 = bkt * DPB;
    const int dd = threadIdx.x & 63;
    const int bq = threadIdx.x >> 6;   // 0..15
    #pragma unroll
    for (int k = 0; k < 2; ++k) {
        const int b = bq + (k << 4);
        const int m = m0 + dd;
        if (m < M) out[(size_t)b * M + m] = acc[dd * 33 + b] + bias[m];
    }
}

// ---- fallback (atomic) path ----
__global__ void k_init_out_t(const float* __restrict__ bias, float* __restrict__ out_t, int M) {
    const int i = blockIdx.x * blockDim.x + threadIdx.x;
    if (i < M * BATCH) out_t[i] = bias[i >> 5];
}

__global__ void k_scatter(const float* __restrict__ xt, const float* __restrict__ values,
                          const int* __restrict__ idx, float* __restrict__ out_t, int E) {
    const int t = blockIdx.x * blockDim.x + threadIdx.x;
    const int e = t >> 5;
    const int b = t & 31;
    if (e < E) {
        const int src = idx[e];
        const int dst = idx[E + e];
        const float contrib = values[e] * xt[(size_t)src * BATCH + b];
        atomicAdd(&out_t[(size_t)dst * BATCH + b], contrib);
    }
}

__global__ void k_transpose_out(const float* __restrict__ out_t, float* __restrict__ out, int M) {
    __shared__ float tile[32][33];
    const int m0 = blockIdx.x * 32;
    const int tx = threadIdx.x;
    const int ty = threadIdx.y;
    #pragma unroll
    for (int k = 0; k < 4; ++k) {
        const int m = m0 + ty + 8 * k;
        if (m < M) tile[ty + 8 * k][tx] = out_t[(size_t)m * BATCH + tx];
    }
    __syncthreads();
    #pragma unroll
    for (int k = 0; k < 4; ++k) {
        const int b = ty + 8 * k;
        const int m = m0 + tx;
        if (m < M) out[(size_t)b * M + m] = tile[tx][b];
    }
}

extern "C" void kernel_launch(void* const* d_in, const int* in_sizes, int n_in,
                              void* d_out, int out_size, void* d_ws, size_t ws_size,
                              hipStream_t stream) {
    const float* x      = (const float*)d_in[0];  // (B,N,1) fp32
    const float* values = (const float*)d_in[1];  // (E,)    fp32
    const float* bias   = (const float*)d_in[2];  // (M,1)   fp32
    const int*   idx    = (const int*)d_in[3];    // (2,E)   int32

    const int N = in_sizes[0] / BATCH;   // 50000
    const int E = in_sizes[3] / 2;       // 1600000
    const int M = in_sizes[2];           // 50000
    const int NB = (M + DPB - 1) / DPB;  // 782

    float* out = (float*)d_out;

    // ---- workspace carve (512B aligned) ----
    char* base = (char*)d_ws;
    size_t off = 0;
    auto carve = [&](size_t bytes) -> void* {
        void* r = base + off;
        off = (off + bytes + 511) & ~(size_t)511;
        return r;
    };
    float* xt       = (float*)carve((size_t)N * BATCH * sizeof(float));  // 6.4 MB
    size_t sv_mark  = off;
    int2*  sv       = (int2*)carve((size_t)E * sizeof(int2));            // 12.8 MB
    int*   gcount   = (int*)carve((size_t)NB * sizeof(int));
    int*   bbase    = (int*)carve((size_t)(NB + 1) * sizeof(int));
    int*   gcursor  = (int*)carve((size_t)NB * sizeof(int));
    const size_t csr_needed = off;
    // fallback out_t overlaps sv (never both live)
    float* out_t = (float*)((char*)d_ws + sv_mark);

    dim3 tblk(32, 8);
    k_transpose_x<<<(N + 31) / 32, tblk, 0, stream>>>(x, xt, N);

    const bool use_csr = (csr_needed <= ws_size) && (N <= 65536) && (NB <= 1024);
    if (use_csr) {
        const size_t hist_bytes = (size_t)NB * sizeof(int);
        k_zero_i32<<<(NB + 255) / 256, 256, 0, stream>>>(gcount, NB);
        k_bucket_count<<<512, 256, hist_bytes, stream>>>(idx, gcount, E, NB);
        k_scan_buckets<<<1, 1024, 0, stream>>>(gcount, bbase, gcursor, NB, E);
        const int chunk = BIN_TPB * BIN_EPT;
        k_bin<<<(E + chunk - 1) / chunk, BIN_TPB, 2 * hist_bytes, stream>>>(idx, values, gcursor, sv, E, NB);
        k_accum<<<NB, ACC_TPB, 0, stream>>>(sv, bbase, xt, bias, out, M);
    } else {
        // fallback: proven atomic path
        k_init_out_t<<<(M * BATCH + 255) / 256, 256, 0, stream>>>(bias, out_t, M);
        const long long total = (long long)E * BATCH;
        k_scatter<<<(int)((total + 255) / 256), 256, 0, stream>>>(xt, values, idx, out_t, E);
        k_transpose_out<<<(M + 31) / 32, tblk, 0, stream>>>(out_t, out, M);
    }
}

// Round 6
// 187.063 us; speedup vs baseline: 2.4583x; 2.4583x over previous
//
#include <hip/hip_runtime.h>

// SpMM: out[b,m] = bias[m] + sum_{e: dst[e]==m} values[e] * x[b, src[e]]
// B=32, N=M=50000, E=1600000.
// v7 post-mortem of v3-v6: k_accum pinned at 347-349us across FOUR provably
// different schedules (incl. asm-pinned 8-deep pipeline) -> the fat-block
// shape itself is cursed (~1.3 outstanding lines/CU by Little's law).
// Round-0's shape (huge grid, tiny blocks, 1 edge-lane/thread, VGPR=8) hit
// 1.8 TB/s on the same gather: on this compiler MLP comes from WAVE COUNT.
// v7: bucket-bin (unchanged) + per-bucket LDS counting sort -> true per-dst
// CSR (sv2 + rowoff), then one HALF-WAVE per dst row: 97 waves/CU TLP,
// register accumulate, zero atomics, one coalesced row-write + bias.

#define BATCH 32
#define DPB   64              // dsts per bucket -> NB = 782
#define BIN_TPB 1024
#define BIN_EPT 4             // chunk = 4096 edges

// ---- transpose x (B,N) -> xt (N,B), LDS tiled ----
__global__ void k_transpose_x(const float* __restrict__ x, float* __restrict__ xt, int N) {
    __shared__ float tile[32][33];
    const int n0 = blockIdx.x * 32;
    const int tx = threadIdx.x;   // 0..31
    const int ty = threadIdx.y;   // 0..7
    #pragma unroll
    for (int k = 0; k < 4; ++k) {
        const int b = ty + 8 * k;
        const int n = n0 + tx;
        tile[tx][b] = (n < N) ? x[(size_t)b * N + n] : 0.0f;
    }
    __syncthreads();
    #pragma unroll
    for (int k = 0; k < 4; ++k) {
        const int n = n0 + ty + 8 * k;
        if (n < N) xt[(size_t)n * BATCH + tx] = tile[ty + 8 * k][tx];
    }
}

__global__ void k_zero_i32(int* __restrict__ p, int n) {
    const int i = blockIdx.x * blockDim.x + threadIdx.x;
    if (i < n) p[i] = 0;
}

// ---- per-bucket global histogram via LDS staging ----
__global__ __launch_bounds__(256) void k_bucket_count(const int* __restrict__ idx,
                                                      int* __restrict__ gcount,
                                                      int E, int NB) {
    extern __shared__ int hist[];
    for (int i = threadIdx.x; i < NB; i += blockDim.x) hist[i] = 0;
    __syncthreads();
    const int stride = gridDim.x * blockDim.x;
    for (int e = blockIdx.x * blockDim.x + threadIdx.x; e < E; e += stride) {
        atomicAdd(&hist[idx[E + e] / DPB], 1);
    }
    __syncthreads();
    for (int i = threadIdx.x; i < NB; i += blockDim.x) {
        if (hist[i]) atomicAdd(&gcount[i], hist[i]);
    }
}

// ---- single-wg exclusive scan of bucket counts (NB <= 1024) ----
__global__ __launch_bounds__(1024) void k_scan_buckets(const int* __restrict__ gcount,
                                                       int* __restrict__ bucket_base,
                                                       int* __restrict__ gcursor,
                                                       int NB, int E) {
    __shared__ int s[1024];
    const int tid = threadIdx.x;
    const int v = (tid < NB) ? gcount[tid] : 0;
    s[tid] = v;
    __syncthreads();
    for (int off = 1; off < 1024; off <<= 1) {
        const int t = (tid >= off) ? s[tid - off] : 0;
        __syncthreads();
        s[tid] += t;
        __syncthreads();
    }
    if (tid < NB) {
        const int excl = s[tid] - v;
        bucket_base[tid] = excl;
        gcursor[tid] = excl;
    }
    if (tid == 0) bucket_base[NB] = E;
}

// ---- bin edges into bucket-contiguous segments, packed (src|dl<<16, val) ----
__global__ __launch_bounds__(BIN_TPB) void k_bin(const int* __restrict__ idx,
                                                 const float* __restrict__ values,
                                                 int* __restrict__ gcursor,
                                                 int2* __restrict__ sv,
                                                 int E, int NB) {
    extern __shared__ int lds[];
    int* hist = lds;          // [NB] counts, then reused as local cursor
    int* base = lds + NB;     // [NB] this chunk's global segment base
    for (int i = threadIdx.x; i < NB; i += BIN_TPB) hist[i] = 0;
    __syncthreads();

    const int c0 = blockIdx.x * (BIN_TPB * BIN_EPT);
    int d[BIN_EPT];
    #pragma unroll
    for (int i = 0; i < BIN_EPT; ++i) {
        const int e = c0 + threadIdx.x + i * BIN_TPB;
        d[i] = (e < E) ? idx[E + e] : -1;
        if (d[i] >= 0) atomicAdd(&hist[d[i] / DPB], 1);
    }
    __syncthreads();
    for (int i = threadIdx.x; i < NB; i += BIN_TPB) {
        const int c = hist[i];
        base[i] = c ? atomicAdd(&gcursor[i], c) : 0;
        hist[i] = 0;
    }
    __syncthreads();
    #pragma unroll
    for (int i = 0; i < BIN_EPT; ++i) {
        if (d[i] >= 0) {
            const int e = c0 + threadIdx.x + i * BIN_TPB;
            const int bkt = d[i] / DPB;
            const int off = atomicAdd(&hist[bkt], 1);
            const int packed = (idx[e] & 0xFFFF) | ((d[i] % DPB) << 16);
            sv[base[bkt] + off] = make_int2(packed, __float_as_int(values[e]));
        }
    }
}

// ---- per-bucket counting sort by dst_local: sv -> sv2, emits rowoff[M+1] ----
// One 256-thread block per bucket. All writes land in the bucket's own 16KB
// window and come from this single block -> no cross-XCD line sharing.
__global__ __launch_bounds__(256) void k_sort64(const int2* __restrict__ sv,
                                                const int* __restrict__ bbase,
                                                int2* __restrict__ sv2,
                                                int* __restrict__ rowoff, int M) {
    __shared__ int cnt[DPB];
    __shared__ int off[DPB + 1];
    __shared__ int cur[DPB];
    const int bkt = blockIdx.x;
    const int beg = bbase[bkt];
    const int end = bbase[bkt + 1];
    const int tid = threadIdx.x;
    if (tid < DPB) cnt[tid] = 0;
    __syncthreads();
    for (int i = beg + tid; i < end; i += 256)
        atomicAdd(&cnt[(sv[i].x >> 16) & 63], 1);
    __syncthreads();
    if (tid == 0) {
        int run = 0;
        #pragma unroll
        for (int k = 0; k < DPB; ++k) { off[k] = run; run += cnt[k]; }
        off[DPB] = run;
    }
    __syncthreads();
    if (tid < DPB) cur[tid] = off[tid];
    __syncthreads();
    for (int i = beg + tid; i < end; i += 256) {
        const int2 a = sv[i];
        const int p = atomicAdd(&cur[(a.x >> 16) & 63], 1);
        sv2[beg + p] = a;
    }
    // per-dst row offsets (global CSR): rowoff[m0+dl] = beg + off[dl]
    const int m0 = bkt * DPB;
    if (tid <= DPB) {
        const int m = m0 + tid;
        if (tid < DPB && m < M) rowoff[m] = beg + off[tid];
        if (m == M) rowoff[M] = beg + off[tid];   // = E at the last bucket
    }
}

// ---- one half-wave per dst row: register accumulate, no atomics ----
__global__ __launch_bounds__(256) void k_gather_rows(const int2* __restrict__ sv2,
                                                     const int* __restrict__ rowoff,
                                                     const float* __restrict__ xt,
                                                     const float* __restrict__ bias,
                                                     float* __restrict__ out_t, int M) {
    const int half = threadIdx.x >> 5;     // 0..7 (dst slot within block)
    const int lb   = threadIdx.x & 31;     // batch lane
    const int m = blockIdx.x * 8 + half;
    if (m >= M) return;
    const int beg = rowoff[m];
    const int end = rowoff[m + 1];
    float a0 = 0.0f, a1 = 0.0f;
    int i = beg;
    for (; i + 1 < end; i += 2) {          // two independent chains
        const int2 e0 = sv2[i];
        const int2 e1 = sv2[i + 1];
        const float x0 = xt[(size_t)(e0.x & 0xFFFF) * BATCH + lb];
        const float x1 = xt[(size_t)(e1.x & 0xFFFF) * BATCH + lb];
        a0 += __int_as_float(e0.y) * x0;
        a1 += __int_as_float(e1.y) * x1;
    }
    if (i < end) {
        const int2 e0 = sv2[i];
        a0 += __int_as_float(e0.y) * xt[(size_t)(e0.x & 0xFFFF) * BATCH + lb];
    }
    out_t[(size_t)m * BATCH + lb] = a0 + a1 + bias[m];
}

// ---- fallback (atomic) path ----
__global__ void k_init_out_t(const float* __restrict__ bias, float* __restrict__ out_t, int M) {
    const int i = blockIdx.x * blockDim.x + threadIdx.x;
    if (i < M * BATCH) out_t[i] = bias[i >> 5];
}

__global__ void k_scatter(const float* __restrict__ xt, const float* __restrict__ values,
                          const int* __restrict__ idx, float* __restrict__ out_t, int E) {
    const int t = blockIdx.x * blockDim.x + threadIdx.x;
    const int e = t >> 5;
    const int b = t & 31;
    if (e < E) {
        const int src = idx[e];
        const int dst = idx[E + e];
        const float contrib = values[e] * xt[(size_t)src * BATCH + b];
        atomicAdd(&out_t[(size_t)dst * BATCH + b], contrib);
    }
}

// ---- transpose out_t (M,32) -> out (32,M), LDS tiled ----
__global__ void k_transpose_out(const float* __restrict__ out_t, float* __restrict__ out, int M) {
    __shared__ float tile[32][33];
    const int m0 = blockIdx.x * 32;
    const int tx = threadIdx.x;
    const int ty = threadIdx.y;
    #pragma unroll
    for (int k = 0; k < 4; ++k) {
        const int m = m0 + ty + 8 * k;
        if (m < M) tile[ty + 8 * k][tx] = out_t[(size_t)m * BATCH + tx];
    }
    __syncthreads();
    #pragma unroll
    for (int k = 0; k < 4; ++k) {
        const int b = ty + 8 * k;
        const int m = m0 + tx;
        if (m < M) out[(size_t)b * M + m] = tile[tx][b];
    }
}

extern "C" void kernel_launch(void* const* d_in, const int* in_sizes, int n_in,
                              void* d_out, int out_size, void* d_ws, size_t ws_size,
                              hipStream_t stream) {
    const float* x      = (const float*)d_in[0];  // (B,N,1) fp32
    const float* values = (const float*)d_in[1];  // (E,)    fp32
    const float* bias   = (const float*)d_in[2];  // (M,1)   fp32
    const int*   idx    = (const int*)d_in[3];    // (2,E)   int32

    const int N = in_sizes[0] / BATCH;   // 50000
    const int E = in_sizes[3] / 2;       // 1600000
    const int M = in_sizes[2];           // 50000
    const int NB = (M + DPB - 1) / DPB;  // 782

    float* out = (float*)d_out;

    // ---- workspace carve (512B aligned); fallback needs only xt+out_t ----
    char* base = (char*)d_ws;
    size_t off = 0;
    auto carve = [&](size_t bytes) -> void* {
        void* r = base + off;
        off = (off + bytes + 511) & ~(size_t)511;
        return r;
    };
    float* xt      = (float*)carve((size_t)N * BATCH * sizeof(float));  // 6.4 MB
    float* out_t   = (float*)carve((size_t)M * BATCH * sizeof(float));  // 6.4 MB
    int2*  sv      = (int2*)carve((size_t)E * sizeof(int2));            // 12.8 MB
    int2*  sv2     = (int2*)carve((size_t)E * sizeof(int2));            // 12.8 MB
    int*   gcount  = (int*)carve((size_t)NB * sizeof(int));
    int*   bbase   = (int*)carve((size_t)(NB + 1) * sizeof(int));
    int*   gcursor = (int*)carve((size_t)NB * sizeof(int));
    int*   rowoff  = (int*)carve((size_t)(M + 1) * sizeof(int));
    const size_t csr_needed = off;

    dim3 tblk(32, 8);
    k_transpose_x<<<(N + 31) / 32, tblk, 0, stream>>>(x, xt, N);

    const bool use_csr = (csr_needed <= ws_size) && (N <= 65536) && (NB <= 1024);
    if (use_csr) {
        const size_t hist_bytes = (size_t)NB * sizeof(int);
        k_zero_i32<<<(NB + 255) / 256, 256, 0, stream>>>(gcount, NB);
        k_bucket_count<<<512, 256, hist_bytes, stream>>>(idx, gcount, E, NB);
        k_scan_buckets<<<1, 1024, 0, stream>>>(gcount, bbase, gcursor, NB, E);
        const int chunk = BIN_TPB * BIN_EPT;
        k_bin<<<(E + chunk - 1) / chunk, BIN_TPB, 2 * hist_bytes, stream>>>(idx, values, gcursor, sv, E, NB);
        k_sort64<<<NB, 256, 0, stream>>>(sv, bbase, sv2, rowoff, M);
        k_gather_rows<<<(M + 7) / 8, 256, 0, stream>>>(sv2, rowoff, xt, bias, out_t, M);
    } else {
        // fallback: proven atomic path
        k_init_out_t<<<(M * BATCH + 255) / 256, 256, 0, stream>>>(bias, out_t, M);
        const long long total = (long long)E * BATCH;
        k_scatter<<<(int)((total + 255) / 256), 256, 0, stream>>>(xt, values, idx, out_t, E);
    }

    k_transpose_out<<<(M + 31) / 32, tblk, 0, stream>>>(out_t, out, M);
}

// Round 7
// 163.707 us; speedup vs baseline: 2.8090x; 1.1427x over previous
//
#include <hip/hip_runtime.h>

// SpMM: out[b,m] = bias[m] + sum_{e: dst[e]==m} values[e] * x[b, src[e]]
// B=32, N=M=50000, E=1600000.
// v8 (from v7=187us): v7 proved wave-count TLP is the lever (gather 347->54us).
// Remaining ~133us is preprocessing. v8: (1) sort64 1024 threads (12->48
// waves/CU) + shfl-scan; (2) gather 4 independent chains (latency-bound at 2);
// (3) bin chunk 4096->8192 (half the reservation rounds); (4) zero fused into
// transpose_x (one fewer dispatch).

#define BATCH 32
#define DPB   64              // dsts per bucket -> NB = 782
#define BIN_TPB 1024
#define BIN_EPT 8             // chunk = 8192 edges

// ---- transpose x (B,N) -> xt (N,B), LDS tiled; block 0 also zeros gcount ----
__global__ void k_transpose_x(const float* __restrict__ x, float* __restrict__ xt,
                              int N, int* __restrict__ gcount, int NB) {
    __shared__ float tile[32][33];
    const int n0 = blockIdx.x * 32;
    const int tx = threadIdx.x;   // 0..31
    const int ty = threadIdx.y;   // 0..7
    if (blockIdx.x == 0) {
        const int tid = ty * 32 + tx;
        for (int i = tid; i < NB; i += 256) gcount[i] = 0;
    }
    #pragma unroll
    for (int k = 0; k < 4; ++k) {
        const int b = ty + 8 * k;
        const int n = n0 + tx;
        tile[tx][b] = (n < N) ? x[(size_t)b * N + n] : 0.0f;
    }
    __syncthreads();
    #pragma unroll
    for (int k = 0; k < 4; ++k) {
        const int n = n0 + ty + 8 * k;
        if (n < N) xt[(size_t)n * BATCH + tx] = tile[ty + 8 * k][tx];
    }
}

// ---- per-bucket global histogram via LDS staging ----
__global__ __launch_bounds__(256) void k_bucket_count(const int* __restrict__ idx,
                                                      int* __restrict__ gcount,
                                                      int E, int NB) {
    extern __shared__ int hist[];
    for (int i = threadIdx.x; i < NB; i += blockDim.x) hist[i] = 0;
    __syncthreads();
    const int stride = gridDim.x * blockDim.x;
    for (int e = blockIdx.x * blockDim.x + threadIdx.x; e < E; e += stride) {
        atomicAdd(&hist[idx[E + e] / DPB], 1);
    }
    __syncthreads();
    for (int i = threadIdx.x; i < NB; i += blockDim.x) {
        if (hist[i]) atomicAdd(&gcount[i], hist[i]);
    }
}

// ---- single-wg exclusive scan of bucket counts (NB <= 1024) ----
__global__ __launch_bounds__(1024) void k_scan_buckets(const int* __restrict__ gcount,
                                                       int* __restrict__ bucket_base,
                                                       int* __restrict__ gcursor,
                                                       int NB, int E) {
    __shared__ int s[1024];
    const int tid = threadIdx.x;
    const int v = (tid < NB) ? gcount[tid] : 0;
    s[tid] = v;
    __syncthreads();
    for (int off = 1; off < 1024; off <<= 1) {
        const int t = (tid >= off) ? s[tid - off] : 0;
        __syncthreads();
        s[tid] += t;
        __syncthreads();
    }
    if (tid < NB) {
        const int excl = s[tid] - v;
        bucket_base[tid] = excl;
        gcursor[tid] = excl;
    }
    if (tid == 0) bucket_base[NB] = E;
}

// ---- bin edges into bucket-contiguous segments, packed (src|dl<<16, val) ----
__global__ __launch_bounds__(BIN_TPB) void k_bin(const int* __restrict__ idx,
                                                 const float* __restrict__ values,
                                                 int* __restrict__ gcursor,
                                                 int2* __restrict__ sv,
                                                 int E, int NB) {
    extern __shared__ int lds[];
    int* hist = lds;          // [NB] counts, then reused as local cursor
    int* base = lds + NB;     // [NB] this chunk's global segment base
    for (int i = threadIdx.x; i < NB; i += BIN_TPB) hist[i] = 0;
    __syncthreads();

    const int c0 = blockIdx.x * (BIN_TPB * BIN_EPT);
    int d[BIN_EPT];
    #pragma unroll
    for (int i = 0; i < BIN_EPT; ++i) {
        const int e = c0 + threadIdx.x + i * BIN_TPB;
        d[i] = (e < E) ? idx[E + e] : -1;
        if (d[i] >= 0) atomicAdd(&hist[d[i] / DPB], 1);
    }
    __syncthreads();
    for (int i = threadIdx.x; i < NB; i += BIN_TPB) {
        const int c = hist[i];
        base[i] = c ? atomicAdd(&gcursor[i], c) : 0;
        hist[i] = 0;
    }
    __syncthreads();
    #pragma unroll
    for (int i = 0; i < BIN_EPT; ++i) {
        if (d[i] >= 0) {
            const int e = c0 + threadIdx.x + i * BIN_TPB;
            const int bkt = d[i] / DPB;
            const int off = atomicAdd(&hist[bkt], 1);
            const int packed = (idx[e] & 0xFFFF) | ((d[i] % DPB) << 16);
            sv[base[bkt] + off] = make_int2(packed, __float_as_int(values[e]));
        }
    }
}

// ---- per-bucket counting sort by dst_local: sv -> sv2, emits rowoff[M+1] ----
// 1024 threads/block (v7 was 256: only 12 waves/CU, latency-bound).
__global__ __launch_bounds__(1024) void k_sort64(const int2* __restrict__ sv,
                                                 const int* __restrict__ bbase,
                                                 int2* __restrict__ sv2,
                                                 int* __restrict__ rowoff, int M) {
    __shared__ int cnt[DPB];
    __shared__ int off[DPB + 1];
    __shared__ int cur[DPB];
    const int bkt = blockIdx.x;
    const int beg = bbase[bkt];
    const int end = bbase[bkt + 1];
    const int tid = threadIdx.x;
    if (tid < DPB) cnt[tid] = 0;
    __syncthreads();
    for (int i = beg + tid; i < end; i += 1024)
        atomicAdd(&cnt[(sv[i].x >> 16) & 63], 1);
    __syncthreads();
    if (tid < DPB) {   // wave 0: 64-lane shuffle inclusive scan
        const int c = cnt[tid];
        int inc = c;
        #pragma unroll
        for (int dlt = 1; dlt < 64; dlt <<= 1) {
            const int t = __shfl_up(inc, dlt, 64);
            if (tid >= dlt) inc += t;
        }
        off[tid] = inc - c;     // exclusive
        cur[tid] = inc - c;
        if (tid == DPB - 1) off[DPB] = inc;
    }
    __syncthreads();
    for (int i = beg + tid; i < end; i += 1024) {
        const int2 a = sv[i];
        const int p = atomicAdd(&cur[(a.x >> 16) & 63], 1);
        sv2[beg + p] = a;
    }
    // per-dst row offsets (global CSR): rowoff[m0+dl] = beg + off[dl]
    const int m0 = bkt * DPB;
    if (tid <= DPB) {
        const int m = m0 + tid;
        if (tid < DPB && m < M) rowoff[m] = beg + off[tid];
        if (m == M) rowoff[M] = beg + off[tid];   // = E at the last bucket
    }
}

// ---- one half-wave per dst row: 4 independent chains, register accumulate ----
__global__ __launch_bounds__(256) void k_gather_rows(const int2* __restrict__ sv2,
                                                     const int* __restrict__ rowoff,
                                                     const float* __restrict__ xt,
                                                     const float* __restrict__ bias,
                                                     float* __restrict__ out_t, int M) {
    const int half = threadIdx.x >> 5;     // 0..7 (dst slot within block)
    const int lb   = threadIdx.x & 31;     // batch lane
    const int m = blockIdx.x * 8 + half;
    if (m >= M) return;
    const int beg = rowoff[m];
    const int end = rowoff[m + 1];
    float a0 = 0.0f, a1 = 0.0f, a2 = 0.0f, a3 = 0.0f;
    int i = beg;
    for (; i + 3 < end; i += 4) {          // four independent chains
        const int2 e0 = sv2[i];
        const int2 e1 = sv2[i + 1];
        const int2 e2 = sv2[i + 2];
        const int2 e3 = sv2[i + 3];
        const float x0 = xt[(size_t)(e0.x & 0xFFFF) * BATCH + lb];
        const float x1 = xt[(size_t)(e1.x & 0xFFFF) * BATCH + lb];
        const float x2 = xt[(size_t)(e2.x & 0xFFFF) * BATCH + lb];
        const float x3 = xt[(size_t)(e3.x & 0xFFFF) * BATCH + lb];
        a0 += __int_as_float(e0.y) * x0;
        a1 += __int_as_float(e1.y) * x1;
        a2 += __int_as_float(e2.y) * x2;
        a3 += __int_as_float(e3.y) * x3;
    }
    for (; i < end; ++i) {
        const int2 e0 = sv2[i];
        a0 += __int_as_float(e0.y) * xt[(size_t)(e0.x & 0xFFFF) * BATCH + lb];
    }
    out_t[(size_t)m * BATCH + lb] = (a0 + a1) + (a2 + a3) + bias[m];
}

// ---- fallback (atomic) path ----
__global__ void k_init_out_t(const float* __restrict__ bias, float* __restrict__ out_t, int M) {
    const int i = blockIdx.x * blockDim.x + threadIdx.x;
    if (i < M * BATCH) out_t[i] = bias[i >> 5];
}

__global__ void k_scatter(const float* __restrict__ xt, const float* __restrict__ values,
                          const int* __restrict__ idx, float* __restrict__ out_t, int E) {
    const int t = blockIdx.x * blockDim.x + threadIdx.x;
    const int e = t >> 5;
    const int b = t & 31;
    if (e < E) {
        const int src = idx[e];
        const int dst = idx[E + e];
        const float contrib = values[e] * xt[(size_t)src * BATCH + b];
        atomicAdd(&out_t[(size_t)dst * BATCH + b], contrib);
    }
}

// ---- transpose out_t (M,32) -> out (32,M), LDS tiled ----
__global__ void k_transpose_out(const float* __restrict__ out_t, float* __restrict__ out, int M) {
    __shared__ float tile[32][33];
    const int m0 = blockIdx.x * 32;
    const int tx = threadIdx.x;
    const int ty = threadIdx.y;
    #pragma unroll
    for (int k = 0; k < 4; ++k) {
        const int m = m0 + ty + 8 * k;
        if (m < M) tile[ty + 8 * k][tx] = out_t[(size_t)m * BATCH + tx];
    }
    __syncthreads();
    #pragma unroll
    for (int k = 0; k < 4; ++k) {
        const int b = ty + 8 * k;
        const int m = m0 + tx;
        if (m < M) out[(size_t)b * M + m] = tile[tx][b];
    }
}

extern "C" void kernel_launch(void* const* d_in, const int* in_sizes, int n_in,
                              void* d_out, int out_size, void* d_ws, size_t ws_size,
                              hipStream_t stream) {
    const float* x      = (const float*)d_in[0];  // (B,N,1) fp32
    const float* values = (const float*)d_in[1];  // (E,)    fp32
    const float* bias   = (const float*)d_in[2];  // (M,1)   fp32
    const int*   idx    = (const int*)d_in[3];    // (2,E)   int32

    const int N = in_sizes[0] / BATCH;   // 50000
    const int E = in_sizes[3] / 2;       // 1600000
    const int M = in_sizes[2];           // 50000
    const int NB = (M + DPB - 1) / DPB;  // 782

    float* out = (float*)d_out;

    // ---- workspace carve (512B aligned); fallback needs only xt+out_t ----
    char* base = (char*)d_ws;
    size_t off = 0;
    auto carve = [&](size_t bytes) -> void* {
        void* r = base + off;
        off = (off + bytes + 511) & ~(size_t)511;
        return r;
    };
    float* xt      = (float*)carve((size_t)N * BATCH * sizeof(float));  // 6.4 MB
    float* out_t   = (float*)carve((size_t)M * BATCH * sizeof(float));  // 6.4 MB
    int2*  sv      = (int2*)carve((size_t)E * sizeof(int2));            // 12.8 MB
    int2*  sv2     = (int2*)carve((size_t)E * sizeof(int2));            // 12.8 MB
    int*   gcount  = (int*)carve((size_t)NB * sizeof(int));
    int*   bbase   = (int*)carve((size_t)(NB + 1) * sizeof(int));
    int*   gcursor = (int*)carve((size_t)NB * sizeof(int));
    int*   rowoff  = (int*)carve((size_t)(M + 1) * sizeof(int));
    const size_t csr_needed = off;

    dim3 tblk(32, 8);
    k_transpose_x<<<(N + 31) / 32, tblk, 0, stream>>>(x, xt, N, gcount, NB);

    const bool use_csr = (csr_needed <= ws_size) && (N <= 65536) && (NB <= 1024);
    if (use_csr) {
        const size_t hist_bytes = (size_t)NB * sizeof(int);
        k_bucket_count<<<512, 256, hist_bytes, stream>>>(idx, gcount, E, NB);
        k_scan_buckets<<<1, 1024, 0, stream>>>(gcount, bbase, gcursor, NB, E);
        const int chunk = BIN_TPB * BIN_EPT;
        k_bin<<<(E + chunk - 1) / chunk, BIN_TPB, 2 * hist_bytes, stream>>>(idx, values, gcursor, sv, E, NB);
        k_sort64<<<NB, 1024, 0, stream>>>(sv, bbase, sv2, rowoff, M);
        k_gather_rows<<<(M + 7) / 8, 256, 0, stream>>>(sv2, rowoff, xt, bias, out_t, M);
    } else {
        // fallback: proven atomic path
        k_init_out_t<<<(M * BATCH + 255) / 256, 256, 0, stream>>>(bias, out_t, M);
        const long long total = (long long)E * BATCH;
        k_scatter<<<(int)((total + 255) / 256), 256, 0, stream>>>(xt, values, idx, out_t, E);
    }

    k_transpose_out<<<(M + 31) / 32, tblk, 0, stream>>>(out_t, out, M);
}